// Round 2
// baseline (3789.044 us; speedup 1.0000x reference)
//
#include <hip/hip_runtime.h>
#include <math.h>

#define BB   64      // batch
#define TT_  1024    // sequence length
#define UU   512     // hidden units
#define VV   256     // vocab (output)
#define EE   256     // embedding dim
#define TC   64      // time chunk

__device__ __forceinline__ float tanh_fast(float x) {
    // tanh(x) = 1 - 2/(e^{2x}+1); abs err ~1e-6 (validated: absmax 6e-5 end-to-end)
    float e = __expf(x + x);
    return 1.f - 2.f * __builtin_amdgcn_rcpf(e + 1.f);
}

// ---------------- E2 = emb @ Wx + b : [256, 512] ----------------
__global__ __launch_bounds__(512) void e2_kernel(
    const float* __restrict__ emb, const float* __restrict__ Wx,
    const float* __restrict__ bias, float* __restrict__ E2)
{
    const int v = blockIdx.x;
    const int u = threadIdx.x;
    float acc = bias[u];
    const float* er = emb + v * EE;
    #pragma unroll 8
    for (int e = 0; e < EE; ++e)
        acc = fmaf(er[e], Wx[e * UU + u], acc);
    E2[v * UU + u] = acc;
}

// ---------------- fused recurrence + logits (chunked, reg-resident weights) ----
// 256 blocks (1/CU), 512 thr = 8 waves. bg = bid&31 (2 batches), ug = bid>>5.
// Group-of-8 blocks (same bg) exchange h via hpub[(slot,b,u)] = (tag<<32|fp32),
// dual-published (volatile sc0 + agent atomic). Poll = baseline-proven: 24
// bounded sc0 rounds, then agent-scope spin with s_sleep (never hangs).
// Weights in REGISTERS: whreg = Wh rows [16ks..+16) x cols quad*4..+4 (64 VGPR);
// wdreg = Wd column slice (64 VGPR). Steady-state LDS = h exchange only,
// XOR-swizzled (float4 index a ^= (a>>3)&7) -> matvec ds_read_b128 conflict-free.
// Matvec: lane (quad = 2w+qsel, ks) accumulates 16k x 4u x 2b; 5x shfl_xor over
// ks; lanes ks<4 tanh+publish one unit each (no partials LDS round-trip).
// Logits: block computes FULL-depth v in [ug*32,+32) for its 2 batches from the
// fully staged h(s-1) -> plain stores (exactly-once; no atomics, no out memset).
__global__ __launch_bounds__(512, 2) void rnn_chunk_kernel(
    const int* __restrict__ toks, const float* __restrict__ E2,
    const float* __restrict__ Wh, const float* __restrict__ Wd,
    const float* __restrict__ bd,
    unsigned long long* hpub,     // [2][BB][UU] (tag,val) pairs
    float* out, int t0, int last)
{
    __shared__ int stok[2][TC];                        // 512 B
    __shared__ __align__(16) float hstage[2][2][UU];   // 8 KB (swizzled)
    __shared__ __align__(16) float xps[2][2][64];      // 1 KB

    const int bid  = blockIdx.x;
    const int bg   = bid & 31;
    const int ug   = bid >> 5;
    const int tid  = threadIdx.x;
    const int w    = tid >> 6;
    const int lane = tid & 63;
    const int b0   = bg * 2;

    // matvec roles
    const int qsel = lane >> 5;          // 0/1
    const int ks   = lane & 31;          // k-slice [ks*16, +16)
    const int quad = w * 2 + qsel;       // unit quad [0,16) -> units quad*4..+4
    // logits roles
    const int vloc8 = lane >> 3;         // [0,8)
    const int us8   = lane & 7;          // u-slice [us8*64, +64)
    const int bL    = w & 1;
    const int vmine = ug * 32 + (w >> 1) * 8 + vloc8;

    // ---- per-dispatch register state (weights are L2/L3-resident: ~2us) ----
    float4 whreg[16];                    // whreg[4g+m] = Wh[16ks+4g+m][ug*64+quad*4..+4]
    {
        const float4* Wh4 = (const float4*)Wh;   // [512][128]
        #pragma unroll
        for (int r = 0; r < 16; ++r)
            whreg[r] = Wh4[(ks * 16 + r) * 128 + ug * 16 + quad];
    }
    float wdreg[64];                     // wdreg[j] = Wd[us8*64+j][vmine]
    #pragma unroll
    for (int j = 0; j < 64; ++j)
        wdreg[j] = Wd[(us8 * 64 + j) * VV + vmine];
    const float bdv = bd[vmine];

    // ---- chunk tokens + xp(t0) staging ----
    if (tid < 128) {
        const int b = tid >> 6, q = tid & 63;
        stok[b][q] = toks[(b0 + b) * TT_ + t0 + q];
        // t0 is even -> xps slot t0&1 == 0
        xps[0][b][q & 63] = 0.f;   // overwritten below; keeps compiler simple
    }
    if (tid < 128) {
        const int b = tid >> 6, u = tid & 63;
        xps[0][b][u] = E2[toks[(b0 + b) * TT_ + t0] * UU + ug * 64 + u];
    }
    __syncthreads();

    for (int tt = 0; tt < TC; ++tt) {
        const int s  = t0 + tt;
        const int sl = (s - 1) & 1;

        // ---- poll h(s-1) (skip own slice except at chunk start) ----
        if (s > 0 && (w != ug || tt == 0)) {
            unsigned long long* a0 = hpub + ((size_t)sl * BB + b0) * UU + w * 64 + lane;
            unsigned long long* a1 = a0 + UU;
            volatile const unsigned long long* f0 = a0;
            volatile const unsigned long long* f1 = a1;
            const unsigned int want = (unsigned int)(s - 1);
            unsigned long long p0 = 0, p1 = 0;
            bool got = false;
            for (int it = 0; it < 24; ++it) {     // sc0 fast rounds (local-XCD L2)
                p0 = *f0; p1 = *f1;
                unsigned long long ok =
                    __ballot((unsigned int)(p0 >> 32) == want) &
                    __ballot((unsigned int)(p1 >> 32) == want);
                if (ok == 0xFFFFFFFFFFFFFFFFull) { got = true; break; }
            }
            if (!got) {                           // proven agent-scope fallback
                while (true) {
                    p0 = __hip_atomic_load(a0, __ATOMIC_RELAXED, __HIP_MEMORY_SCOPE_AGENT);
                    p1 = __hip_atomic_load(a1, __ATOMIC_RELAXED, __HIP_MEMORY_SCOPE_AGENT);
                    unsigned long long ok =
                        __ballot((unsigned int)(p0 >> 32) == want) &
                        __ballot((unsigned int)(p1 >> 32) == want);
                    if (ok == 0xFFFFFFFFFFFFFFFFull) break;
                    __builtin_amdgcn_s_sleep(1);
                }
            }
            // stage swizzled: u = w*64+lane -> float4 a = w*16+(lane>>2), elem lane&3
            const int aa  = w * 16 + (lane >> 2);
            const int asw = aa ^ ((aa >> 3) & 7);
            const int fi  = asw * 4 + (lane & 3);
            hstage[sl][0][fi] = __uint_as_float((unsigned int)p0);
            hstage[sl][1][fi] = __uint_as_float((unsigned int)p1);
        }
        __syncthreads();

        // ---- xp prefetch for s+1: issue load now, LDS-write after matvec ----
        float xpre = 0.f;
        const bool dopre = (tid < 128) && (tt + 1 < TC);
        if (dopre)
            xpre = E2[stok[tid >> 6][tt + 1] * UU + ug * 64 + (tid & 63)];

        // ---- Wh matvec from registers; h(s-1) from swizzled LDS ----
        float acc0[4] = {0.f, 0.f, 0.f, 0.f};
        float acc1[4] = {0.f, 0.f, 0.f, 0.f};
        if (s > 0) {
            const float* H0 = hstage[sl][0];
            const float* H1 = hstage[sl][1];
            const int vsw = (ks >> 1) & 7;
            #pragma unroll
            for (int g = 0; g < 4; ++g) {
                const int as2 = (4 * ks + g) ^ vsw;
                const float4 ha = *(const float4*)(H0 + as2 * 4);
                const float4 hc = *(const float4*)(H1 + as2 * 4);
                const float av[4] = {ha.x, ha.y, ha.z, ha.w};
                const float cv[4] = {hc.x, hc.y, hc.z, hc.w};
                #pragma unroll
                for (int m = 0; m < 4; ++m) {
                    const float4 wv = whreg[g * 4 + m];
                    acc0[0] = fmaf(av[m], wv.x, acc0[0]);
                    acc0[1] = fmaf(av[m], wv.y, acc0[1]);
                    acc0[2] = fmaf(av[m], wv.z, acc0[2]);
                    acc0[3] = fmaf(av[m], wv.w, acc0[3]);
                    acc1[0] = fmaf(cv[m], wv.x, acc1[0]);
                    acc1[1] = fmaf(cv[m], wv.y, acc1[1]);
                    acc1[2] = fmaf(cv[m], wv.z, acc1[2]);
                    acc1[3] = fmaf(cv[m], wv.w, acc1[3]);
                }
            }
            // reduce over ks (5 levels); every lane ends with the full sums
            #pragma unroll
            for (int off = 1; off < 32; off <<= 1) {
                #pragma unroll
                for (int c = 0; c < 4; ++c) {
                    acc0[c] += __shfl_xor(acc0[c], off, 64);
                    acc1[c] += __shfl_xor(acc1[c], off, 64);
                }
            }
        }
        // deferred xp LDS write (load latency hidden under matvec)
        if (dopre)
            xps[(s + 1) & 1][tid >> 6][tid & 63] = xpre;

        // ---- finalize + publish h(s): lanes ks<4, one unit each (c = ks) ----
        if (ks < 4) {
            const int c  = ks;
            const float h0 = tanh_fast(acc0[c] + xps[s & 1][0][quad * 4 + c]);
            const float h1 = tanh_fast(acc1[c] + xps[s & 1][1][quad * 4 + c]);
            unsigned long long* dst0 =
                hpub + ((size_t)(s & 1) * BB + b0) * UU + ug * 64 + quad * 4 + c;
            unsigned long long* dst1 = dst0 + UU;
            const unsigned long long tg = (unsigned long long)(unsigned int)s << 32;
            const unsigned long long pk0 = tg | __float_as_uint(h0);
            const unsigned long long pk1 = tg | __float_as_uint(h1);
            *(volatile unsigned long long*)dst0 = pk0;   // sc0 local-L2 copy
            *(volatile unsigned long long*)dst1 = pk1;
            __hip_atomic_store(dst0, pk0, __ATOMIC_RELAXED, __HIP_MEMORY_SCOPE_AGENT);
            __hip_atomic_store(dst1, pk1, __ATOMIC_RELAXED, __HIP_MEMORY_SCOPE_AGENT);
            const int af  = ug * 16 + quad;
            const int asf = af ^ ((af >> 3) & 7);
            hstage[s & 1][0][asf * 4 + c] = h0;
            hstage[s & 1][1][asf * 4 + c] = h1;
        }

        // ---- logits(s-1): full depth, v-slice, plain store (self-balancing:
        //      runs while peer blocks publish h(s)) ----
        if (s > 0) {
            const float* HB = hstage[sl][bL];
            const int lb  = us8 * 16;
            const int vlo = (2 * us8) & 7;
            const int vhi = (2 * us8 + 1) & 7;
            float l0 = 0.f, l1 = 0.f, l2 = 0.f, l3 = 0.f;
            #pragma unroll
            for (int j = 0; j < 16; ++j) {
                const int as4 = (lb + j) ^ (j < 8 ? vlo : vhi);
                const float4 h4 = *(const float4*)(HB + as4 * 4);
                l0 = fmaf(h4.x, wdreg[4 * j + 0], l0);
                l1 = fmaf(h4.y, wdreg[4 * j + 1], l1);
                l2 = fmaf(h4.z, wdreg[4 * j + 2], l2);
                l3 = fmaf(h4.w, wdreg[4 * j + 3], l3);
            }
            float sum = (l0 + l1) + (l2 + l3);
            sum += __shfl_xor(sum, 1, 64);
            sum += __shfl_xor(sum, 2, 64);
            sum += __shfl_xor(sum, 4, 64);
            if (us8 == 0)
                out[((size_t)(b0 + bL) * TT_ + (s - 1)) * VV + vmine] = sum + bdv;
        }
    }

    // ---- last chunk epilogue: logits(1023) needs full h(1023) staged ----
    if (last) {
        const int s  = t0 + TC - 1;          // 1023
        const int sl = s & 1;
        if (w != ug) {   // own slice already in hstage from tt=63 finalize
            unsigned long long* a0 = hpub + ((size_t)sl * BB + b0) * UU + w * 64 + lane;
            unsigned long long* a1 = a0 + UU;
            volatile const unsigned long long* f0 = a0;
            volatile const unsigned long long* f1 = a1;
            const unsigned int want = (unsigned int)s;
            unsigned long long p0 = 0, p1 = 0;
            bool got = false;
            for (int it = 0; it < 24; ++it) {
                p0 = *f0; p1 = *f1;
                unsigned long long ok =
                    __ballot((unsigned int)(p0 >> 32) == want) &
                    __ballot((unsigned int)(p1 >> 32) == want);
                if (ok == 0xFFFFFFFFFFFFFFFFull) { got = true; break; }
            }
            if (!got) {
                while (true) {
                    p0 = __hip_atomic_load(a0, __ATOMIC_RELAXED, __HIP_MEMORY_SCOPE_AGENT);
                    p1 = __hip_atomic_load(a1, __ATOMIC_RELAXED, __HIP_MEMORY_SCOPE_AGENT);
                    unsigned long long ok =
                        __ballot((unsigned int)(p0 >> 32) == want) &
                        __ballot((unsigned int)(p1 >> 32) == want);
                    if (ok == 0xFFFFFFFFFFFFFFFFull) break;
                    __builtin_amdgcn_s_sleep(1);
                }
            }
            const int aa  = w * 16 + (lane >> 2);
            const int asw = aa ^ ((aa >> 3) & 7);
            const int fi  = asw * 4 + (lane & 3);
            hstage[sl][0][fi] = __uint_as_float((unsigned int)p0);
            hstage[sl][1][fi] = __uint_as_float((unsigned int)p1);
        }
        __syncthreads();
        {
            const float* HB = hstage[sl][bL];
            const int lb  = us8 * 16;
            const int vlo = (2 * us8) & 7;
            const int vhi = (2 * us8 + 1) & 7;
            float l0 = 0.f, l1 = 0.f, l2 = 0.f, l3 = 0.f;
            #pragma unroll
            for (int j = 0; j < 16; ++j) {
                const int as4 = (lb + j) ^ (j < 8 ? vlo : vhi);
                const float4 h4 = *(const float4*)(HB + as4 * 4);
                l0 = fmaf(h4.x, wdreg[4 * j + 0], l0);
                l1 = fmaf(h4.y, wdreg[4 * j + 1], l1);
                l2 = fmaf(h4.z, wdreg[4 * j + 2], l2);
                l3 = fmaf(h4.w, wdreg[4 * j + 3], l3);
            }
            float sum = (l0 + l1) + (l2 + l3);
            sum += __shfl_xor(sum, 1, 64);
            sum += __shfl_xor(sum, 2, 64);
            sum += __shfl_xor(sum, 4, 64);
            if (us8 == 0)
                out[((size_t)(b0 + bL) * TT_ + s) * VV + vmine] = sum + bdv;
        }
    }
}

extern "C" void kernel_launch(void* const* d_in, const int* in_sizes, int n_in,
                              void* d_out, int out_size, void* d_ws, size_t ws_size,
                              hipStream_t stream)
{
    (void)in_sizes; (void)n_in; (void)ws_size; (void)out_size;

    const int*   toks = (const int*)  d_in[0];
    const float* emb  = (const float*)d_in[1];
    const float* Wx   = (const float*)d_in[2];
    const float* Wh   = (const float*)d_in[3];
    const float* bias = (const float*)d_in[4];
    const float* Wd   = (const float*)d_in[5];
    const float* bd   = (const float*)d_in[6];
    float* out = (float*)d_out;

    // ws layout: hpub [2*BB*UU] u64 (512 KB) | E2 [EE*UU] f32 (512 KB)
    unsigned long long* hpub = (unsigned long long*)d_ws;
    float* E2 = (float*)(hpub + 2 * BB * UU);

    // invalidate tags (0xFFFFFFFF matches no step) -> no stale-tag match on first run
    hipMemsetAsync(hpub, 0xFF, (size_t)(2 * BB * UU) * sizeof(unsigned long long), stream);
    e2_kernel<<<EE, UU, 0, stream>>>(emb, Wx, bias, E2);

    for (int c = 0; c < TT_ / TC; ++c) {
        const int t0 = c * TC;
        rnn_chunk_kernel<<<256, 512, 0, stream>>>(
            toks, E2, Wh, Wd, bd, hpub, out, t0, c == (TT_ / TC - 1));
    }
}

// Round 4
// 3569.883 us; speedup vs baseline: 1.0614x; 1.0614x over previous
//
#include <hip/hip_runtime.h>
#include <math.h>

#define BB   64      // batch
#define TT_  1024    // sequence length
#define UU   512     // hidden units
#define VV   256     // vocab (output)
#define EE   256     // embedding dim
#define TC   128     // time chunk (8 dispatches)

__device__ __forceinline__ float tanh_fast(float x) {
    // tanh(x) = 1 - 2/(e^{2x}+1); abs err ~1e-6 (validated: absmax 6e-5 end-to-end)
    float e = __expf(x + x);
    return 1.f - 2.f * __builtin_amdgcn_rcpf(e + 1.f);
}

// LDS float4-index swizzle: f(a) uses only bits >=3, XOR modifies bits 0..2.
// Conflict-free (verified by enumeration) for BOTH hot read patterns:
//  - matvec: a = 4*ks+g      -> per-16-lane phase: 8 bank-groups x 2 lanes (free)
//  - logits: a = 16*us8+j    -> 8 distinct bank-groups across us8=0..7
// (R2's f=(a>>3)&7 left a 2-way conflict on logits: only 4 distinct XOR vals ->
//  SQ_LDS_BANK_CONFLICT 1.26e7. The (a>>6)&1 term fixes it.)
__device__ __forceinline__ int swz(int a) {
    return a ^ (((a >> 3) & 7) ^ ((a >> 6) & 1));
}

// ---------------- E2 = emb @ Wx + b : [256, 512] ----------------
__global__ __launch_bounds__(512) void e2_kernel(
    const float* __restrict__ emb, const float* __restrict__ Wx,
    const float* __restrict__ bias, float* __restrict__ E2)
{
    const int v = blockIdx.x;
    const int u = threadIdx.x;
    float acc = bias[u];
    const float* er = emb + v * EE;
    #pragma unroll 8
    for (int e = 0; e < EE; ++e)
        acc = fmaf(er[e], Wx[e * UU + u], acc);
    E2[v * UU + u] = acc;
}

// ---------------- fused recurrence + logits (chunked, reg-resident weights) ----
// 256 blocks (1/CU), 512 thr = 8 waves. bg = bid&31 (2 batches), ug = bid>>5.
// Group-of-8 blocks (same bg) exchange h via hpub[(slot,b,u)] = (tag<<32|fp32),
// dual-published (volatile sc0 + agent atomic). Poll = baseline-proven: 24
// bounded sc0 rounds, then agent-scope spin with s_sleep (never hangs).
// waves_per_eu(2,2): VGPR budget up to 512 (R2's launch_bounds(512,2) capped at
// ~128 and demoted whreg -> L2 remat every step -> 242us). whreg pinned via
// SCALAR asm temps (float4 "+v" operands don't compile on gfx950 backend).
// Weights in REGISTERS: whreg (64 VGPR) + wdreg (64 VGPR). Steady-state LDS =
// h exchange only, swz()-swizzled -> matvec AND logits ds_read_b128 conflict-free.
// Matvec: lane (quad = 2w+qsel, ks) accumulates 16k x 4u x 2b; 5x shfl_xor over
// ks; lanes ks<4 tanh+publish one unit each (no partials LDS round-trip).
// Logits: block computes FULL-depth v in [ug*32,+32) for its 2 batches from the
// fully staged h(s-1) -> plain stores (exactly-once; no atomics, no out memset).
__global__ __launch_bounds__(512)
__attribute__((amdgpu_waves_per_eu(2, 2)))
void rnn_chunk_kernel(
    const int* __restrict__ toks, const float* __restrict__ E2,
    const float* __restrict__ Wh, const float* __restrict__ Wd,
    const float* __restrict__ bd,
    unsigned long long* hpub,     // [2][BB][UU] (tag,val) pairs
    float* out, int t0, int last)
{
    __shared__ int stok[2][TC];                        // 1 KB
    __shared__ __align__(16) float hstage[2][2][UU];   // 8 KB (swizzled)
    __shared__ __align__(16) float xps[2][2][64];      // 1 KB

    const int bid  = blockIdx.x;
    const int bg   = bid & 31;
    const int ug   = bid >> 5;
    const int tid  = threadIdx.x;
    const int w    = tid >> 6;
    const int lane = tid & 63;
    const int b0   = bg * 2;

    // matvec roles
    const int qsel = lane >> 5;          // 0/1
    const int ks   = lane & 31;          // k-slice [ks*16, +16)
    const int quad = w * 2 + qsel;       // unit quad [0,16) -> units quad*4..+4
    const int fmv  = ((ks >> 1) & 7) ^ ((ks >> 4) & 1);   // swz term, matvec reads
    // logits roles
    const int vloc8 = lane >> 3;         // [0,8)
    const int us8   = lane & 7;          // u-slice [us8*64, +64)
    const int bL    = w & 1;
    const int vmine = ug * 32 + (w >> 1) * 8 + vloc8;

    // ---- per-dispatch register state (weights are L2/L3-resident) ----
    float4 whreg[16];                    // whreg[4g+m] = Wh[16ks+4g+m][ug*64+quad*4..+4]
    {
        const float4* Wh4 = (const float4*)Wh;   // [512][128]
        #pragma unroll
        for (int r = 0; r < 16; ++r)
            whreg[r] = Wh4[(ks * 16 + r) * 128 + ug * 16 + quad];
    }
    // pin via scalar temps: asm defs can't be rematerialized from the load,
    // so whreg must stay VGPR-resident (float4 "+v" asm operands don't compile)
    #pragma unroll
    for (int r = 0; r < 16; ++r) {
        float px = whreg[r].x, py = whreg[r].y, pz = whreg[r].z, pw = whreg[r].w;
        asm volatile("" : "+v"(px), "+v"(py), "+v"(pz), "+v"(pw));
        whreg[r] = make_float4(px, py, pz, pw);
    }

    float wdreg[64];                     // wdreg[j] = Wd[us8*64+j][vmine]
    #pragma unroll
    for (int j = 0; j < 64; ++j)
        wdreg[j] = Wd[(us8 * 64 + j) * VV + vmine];
    const float bdv = bd[vmine];

    // ---- chunk tokens + xp(t0) staging ----
    if (tid < 256) {
        const int b = tid >> 7, q = tid & 127;
        stok[b][q] = toks[(b0 + b) * TT_ + t0 + q];
    }
    if (tid < 128) {
        const int b = tid >> 6, u = tid & 63;
        xps[0][b][u] = E2[toks[(b0 + b) * TT_ + t0] * UU + ug * 64 + u];
    }
    __syncthreads();

    for (int tt = 0; tt < TC; ++tt) {
        const int s  = t0 + tt;
        const int sl = (s - 1) & 1;

        // ---- poll h(s-1) (skip own slice except at chunk start) ----
        if (s > 0 && (w != ug || tt == 0)) {
            unsigned long long* a0 = hpub + ((size_t)sl * BB + b0) * UU + w * 64 + lane;
            unsigned long long* a1 = a0 + UU;
            volatile const unsigned long long* f0 = a0;
            volatile const unsigned long long* f1 = a1;
            const unsigned int want = (unsigned int)(s - 1);
            unsigned long long p0 = 0, p1 = 0;
            bool got = false;
            for (int it = 0; it < 24; ++it) {     // sc0 fast rounds (local-XCD L2)
                p0 = *f0; p1 = *f1;
                unsigned long long ok =
                    __ballot((unsigned int)(p0 >> 32) == want) &
                    __ballot((unsigned int)(p1 >> 32) == want);
                if (ok == 0xFFFFFFFFFFFFFFFFull) { got = true; break; }
            }
            if (!got) {                           // proven agent-scope fallback
                while (true) {
                    p0 = __hip_atomic_load(a0, __ATOMIC_RELAXED, __HIP_MEMORY_SCOPE_AGENT);
                    p1 = __hip_atomic_load(a1, __ATOMIC_RELAXED, __HIP_MEMORY_SCOPE_AGENT);
                    unsigned long long ok =
                        __ballot((unsigned int)(p0 >> 32) == want) &
                        __ballot((unsigned int)(p1 >> 32) == want);
                    if (ok == 0xFFFFFFFFFFFFFFFFull) break;
                    __builtin_amdgcn_s_sleep(1);
                }
            }
            // stage swizzled: u = w*64+lane -> float4 a = w*16+(lane>>2), elem lane&3
            const int aa = w * 16 + (lane >> 2);
            const int fi = swz(aa) * 4 + (lane & 3);
            hstage[sl][0][fi] = __uint_as_float((unsigned int)p0);
            hstage[sl][1][fi] = __uint_as_float((unsigned int)p1);
        }
        __syncthreads();

        // ---- xp prefetch for s+1: issue load now, LDS-write after matvec ----
        float xpre = 0.f;
        const bool dopre = (tid < 128) && (tt + 1 < TC);
        if (dopre)
            xpre = E2[stok[tid >> 6][tt + 1] * UU + ug * 64 + (tid & 63)];

        // ---- Wh matvec from registers; h(s-1) from swizzled LDS ----
        float acc0[4] = {0.f, 0.f, 0.f, 0.f};
        float acc1[4] = {0.f, 0.f, 0.f, 0.f};
        if (s > 0) {
            const float* H0 = hstage[sl][0];
            const float* H1 = hstage[sl][1];
            #pragma unroll
            for (int g = 0; g < 4; ++g) {
                const int as2 = (4 * ks + g) ^ fmv;
                const float4 ha = *(const float4*)(H0 + as2 * 4);
                const float4 hc = *(const float4*)(H1 + as2 * 4);
                const float av[4] = {ha.x, ha.y, ha.z, ha.w};
                const float cv[4] = {hc.x, hc.y, hc.z, hc.w};
                #pragma unroll
                for (int m = 0; m < 4; ++m) {
                    const float4 wv = whreg[g * 4 + m];
                    acc0[0] = fmaf(av[m], wv.x, acc0[0]);
                    acc0[1] = fmaf(av[m], wv.y, acc0[1]);
                    acc0[2] = fmaf(av[m], wv.z, acc0[2]);
                    acc0[3] = fmaf(av[m], wv.w, acc0[3]);
                    acc1[0] = fmaf(cv[m], wv.x, acc1[0]);
                    acc1[1] = fmaf(cv[m], wv.y, acc1[1]);
                    acc1[2] = fmaf(cv[m], wv.z, acc1[2]);
                    acc1[3] = fmaf(cv[m], wv.w, acc1[3]);
                }
            }
            // reduce over ks (5 levels); every lane ends with the full sums
            #pragma unroll
            for (int off = 1; off < 32; off <<= 1) {
                #pragma unroll
                for (int c = 0; c < 4; ++c) {
                    acc0[c] += __shfl_xor(acc0[c], off, 64);
                    acc1[c] += __shfl_xor(acc1[c], off, 64);
                }
            }
        }
        // deferred xp LDS write (load latency hidden under matvec)
        if (dopre)
            xps[(s + 1) & 1][tid >> 6][tid & 63] = xpre;

        // ---- finalize + publish h(s): lanes ks<4, one unit each (c = ks) ----
        if (ks < 4) {
            const int c  = ks;
            const float h0 = tanh_fast(acc0[c] + xps[s & 1][0][quad * 4 + c]);
            const float h1 = tanh_fast(acc1[c] + xps[s & 1][1][quad * 4 + c]);
            unsigned long long* dst0 =
                hpub + ((size_t)(s & 1) * BB + b0) * UU + ug * 64 + quad * 4 + c;
            unsigned long long* dst1 = dst0 + UU;
            const unsigned long long tg = (unsigned long long)(unsigned int)s << 32;
            const unsigned long long pk0 = tg | __float_as_uint(h0);
            const unsigned long long pk1 = tg | __float_as_uint(h1);
            *(volatile unsigned long long*)dst0 = pk0;   // sc0 local-L2 copy
            *(volatile unsigned long long*)dst1 = pk1;
            __hip_atomic_store(dst0, pk0, __ATOMIC_RELAXED, __HIP_MEMORY_SCOPE_AGENT);
            __hip_atomic_store(dst1, pk1, __ATOMIC_RELAXED, __HIP_MEMORY_SCOPE_AGENT);
            const int af  = ug * 16 + quad;
            const int asf = swz(af);
            hstage[s & 1][0][asf * 4 + c] = h0;
            hstage[s & 1][1][asf * 4 + c] = h1;
        }

        // ---- logits(s-1): full depth, v-slice, plain store (self-balancing:
        //      runs while peer blocks publish h(s)) ----
        if (s > 0) {
            const float* HB = hstage[sl][bL];
            float l0 = 0.f, l1 = 0.f, l2 = 0.f, l3 = 0.f;
            #pragma unroll
            for (int j = 0; j < 16; ++j) {
                const int as4 = swz(us8 * 16 + j);
                const float4 h4 = *(const float4*)(HB + as4 * 4);
                l0 = fmaf(h4.x, wdreg[4 * j + 0], l0);
                l1 = fmaf(h4.y, wdreg[4 * j + 1], l1);
                l2 = fmaf(h4.z, wdreg[4 * j + 2], l2);
                l3 = fmaf(h4.w, wdreg[4 * j + 3], l3);
            }
            float sum = (l0 + l1) + (l2 + l3);
            sum += __shfl_xor(sum, 1, 64);
            sum += __shfl_xor(sum, 2, 64);
            sum += __shfl_xor(sum, 4, 64);
            if (us8 == 0)
                out[((size_t)(b0 + bL) * TT_ + (s - 1)) * VV + vmine] = sum + bdv;
        }
    }

    // ---- last chunk epilogue: logits(1023) needs full h(1023) staged ----
    if (last) {
        const int s  = t0 + TC - 1;          // 1023
        const int sl = s & 1;
        if (w != ug) {   // own slice already in hstage from tt=TC-1 finalize
            unsigned long long* a0 = hpub + ((size_t)sl * BB + b0) * UU + w * 64 + lane;
            unsigned long long* a1 = a0 + UU;
            volatile const unsigned long long* f0 = a0;
            volatile const unsigned long long* f1 = a1;
            const unsigned int want = (unsigned int)s;
            unsigned long long p0 = 0, p1 = 0;
            bool got = false;
            for (int it = 0; it < 24; ++it) {
                p0 = *f0; p1 = *f1;
                unsigned long long ok =
                    __ballot((unsigned int)(p0 >> 32) == want) &
                    __ballot((unsigned int)(p1 >> 32) == want);
                if (ok == 0xFFFFFFFFFFFFFFFFull) { got = true; break; }
            }
            if (!got) {
                while (true) {
                    p0 = __hip_atomic_load(a0, __ATOMIC_RELAXED, __HIP_MEMORY_SCOPE_AGENT);
                    p1 = __hip_atomic_load(a1, __ATOMIC_RELAXED, __HIP_MEMORY_SCOPE_AGENT);
                    unsigned long long ok =
                        __ballot((unsigned int)(p0 >> 32) == want) &
                        __ballot((unsigned int)(p1 >> 32) == want);
                    if (ok == 0xFFFFFFFFFFFFFFFFull) break;
                    __builtin_amdgcn_s_sleep(1);
                }
            }
            const int aa = w * 16 + (lane >> 2);
            const int fi = swz(aa) * 4 + (lane & 3);
            hstage[sl][0][fi] = __uint_as_float((unsigned int)p0);
            hstage[sl][1][fi] = __uint_as_float((unsigned int)p1);
        }
        __syncthreads();
        {
            const float* HB = hstage[sl][bL];
            float l0 = 0.f, l1 = 0.f, l2 = 0.f, l3 = 0.f;
            #pragma unroll
            for (int j = 0; j < 16; ++j) {
                const int as4 = swz(us8 * 16 + j);
                const float4 h4 = *(const float4*)(HB + as4 * 4);
                l0 = fmaf(h4.x, wdreg[4 * j + 0], l0);
                l1 = fmaf(h4.y, wdreg[4 * j + 1], l1);
                l2 = fmaf(h4.z, wdreg[4 * j + 2], l2);
                l3 = fmaf(h4.w, wdreg[4 * j + 3], l3);
            }
            float sum = (l0 + l1) + (l2 + l3);
            sum += __shfl_xor(sum, 1, 64);
            sum += __shfl_xor(sum, 2, 64);
            sum += __shfl_xor(sum, 4, 64);
            if (us8 == 0)
                out[((size_t)(b0 + bL) * TT_ + s) * VV + vmine] = sum + bdv;
        }
    }
}

extern "C" void kernel_launch(void* const* d_in, const int* in_sizes, int n_in,
                              void* d_out, int out_size, void* d_ws, size_t ws_size,
                              hipStream_t stream)
{
    (void)in_sizes; (void)n_in; (void)ws_size; (void)out_size;

    const int*   toks = (const int*)  d_in[0];
    const float* emb  = (const float*)d_in[1];
    const float* Wx   = (const float*)d_in[2];
    const float* Wh   = (const float*)d_in[3];
    const float* bias = (const float*)d_in[4];
    const float* Wd   = (const float*)d_in[5];
    const float* bd   = (const float*)d_in[6];
    float* out = (float*)d_out;

    // ws layout: hpub [2*BB*UU] u64 (512 KB) | E2 [EE*UU] f32 (512 KB)
    unsigned long long* hpub = (unsigned long long*)d_ws;
    float* E2 = (float*)(hpub + 2 * BB * UU);

    // invalidate tags (0xFFFFFFFF matches no step) -> no stale-tag match on first run
    hipMemsetAsync(hpub, 0xFF, (size_t)(2 * BB * UU) * sizeof(unsigned long long), stream);
    e2_kernel<<<EE, UU, 0, stream>>>(emb, Wx, bias, E2);

    for (int c = 0; c < TT_ / TC; ++c) {
        const int t0 = c * TC;
        rnn_chunk_kernel<<<256, 512, 0, stream>>>(
            toks, E2, Wh, Wd, bd, hpub, out, t0, c == (TT_ / TC - 1));
    }
}